// Round 10
// baseline (295.419 us; speedup 1.0000x reference)
//
#include <hip/hip_runtime.h>

#define N_NODES 50000
#define N_EDGES 800000
#define NB 196  // ceil(N_NODES / 256)

typedef unsigned int uint;
typedef short bf16x8 __attribute__((ext_vector_type(8)));
typedef float f32x4 __attribute__((ext_vector_type(4)));

__device__ __forceinline__ ushort f2bf(float f) {
    union { float f; uint u; } v; v.f = f;
    uint r = (v.u + 0x7FFFu + ((v.u >> 16) & 1u)) >> 16;  // RNE
    return (ushort)r;
}
__device__ __forceinline__ float bf_lo(uint u) { return __uint_as_float(u << 16); }
__device__ __forceinline__ float bf_hi(uint u) { return __uint_as_float(u & 0xFFFF0000u); }

// ---------- fp32 -> bf16, CHUNK-MAJOR layout: out[c8][node][16 feats] ----------
// 8 chunks of 16 features; chunk row = 32B = 8 uints. Thread: 8 floats.
__global__ void k_tobf16c(const float* __restrict__ in, uint* __restrict__ out) {
    int t = blockIdx.x * 256 + threadIdx.x;   // over N*16 parts
    int node = t >> 4, part = t & 15;
    const float4* i4 = (const float4*)in + (size_t)t * 2;
    float4 v0 = i4[0], v1 = i4[1];
    uint4 o;
    o.x = (uint)f2bf(v0.x) | ((uint)f2bf(v0.y) << 16);
    o.y = (uint)f2bf(v0.z) | ((uint)f2bf(v0.w) << 16);
    o.z = (uint)f2bf(v1.x) | ((uint)f2bf(v1.y) << 16);
    o.w = (uint)f2bf(v1.z) | ((uint)f2bf(v1.w) << 16);
    int c8 = part >> 1, half = part & 1;
    ((uint4*)out)[((size_t)c8 * N_NODES + node) * 2 + half] = o;
}

// ---------- W12 = W1@W2 (bf16, col-major-by-row) and bvec = b1@W2 ----------
__global__ void k_w12(const float* __restrict__ W1, const float* __restrict__ W2,
                      const float* __restrict__ b1, ushort* __restrict__ W12t,
                      float* __restrict__ bvec) {
    int n = threadIdx.x;
    int k = blockIdx.x;
    float s = 0.f;
    if (k < 128) {
        for (int m = 0; m < 256; ++m) s = fmaf(W1[(size_t)k * 256 + m], W2[(size_t)m * 128 + n], s);
        W12t[(size_t)n * 128 + k] = f2bf(s);
    } else {
        for (int m = 0; m < 256; ++m) s = fmaf(b1[m], W2[(size_t)m * 128 + n], s);
        bvec[n] = s;
    }
}

// ---------- degree / CSR build ----------

__global__ void k_zero(int* counts) {
    int i = blockIdx.x * 256 + threadIdx.x;
    if (i < N_NODES) counts[i] = 0;
}

__global__ void k_histrank(const int* __restrict__ dst, int* __restrict__ counts,
                           ushort* __restrict__ rank) {
    int e = blockIdx.x * 256 + threadIdx.x;
    if (e < N_EDGES) rank[e] = (ushort)atomicAdd(&counts[dst[e]], 1);
}

__global__ void k_blocksum(const int* __restrict__ counts, int* __restrict__ bsum) {
    __shared__ int lds[256];
    int t = threadIdx.x;
    int i = blockIdx.x * 256 + t;
    int v = (i < N_NODES) ? counts[i] : 0;
    lds[t] = v;
    __syncthreads();
    for (int off = 128; off > 0; off >>= 1) {
        if (t < off) lds[t] += lds[t + off];
        __syncthreads();
    }
    if (t == 0) bsum[blockIdx.x] = lds[0];
}

__global__ void k_scanb(const int* __restrict__ bsum, int* __restrict__ boff) {
    __shared__ int lds[256];
    int t = threadIdx.x;
    int v = (t < NB) ? bsum[t] : 0;
    lds[t] = v;
    __syncthreads();
    for (int off = 1; off < 256; off <<= 1) {
        int o = (t >= off) ? lds[t - off] : 0;
        __syncthreads();
        lds[t] += o;
        __syncthreads();
    }
    if (t < NB) boff[t] = lds[t] - v;  // exclusive
}

__global__ void k_scatter_rp(const int* __restrict__ counts, const int* __restrict__ boff,
                             int* __restrict__ row_ptr, float* __restrict__ dinv) {
    __shared__ int lds[256];
    int t = threadIdx.x;
    int i = blockIdx.x * 256 + t;
    int v = (i < N_NODES) ? counts[i] : 0;
    lds[t] = v;
    __syncthreads();
    for (int off = 1; off < 256; off <<= 1) {
        int o = (t >= off) ? lds[t - off] : 0;
        __syncthreads();
        lds[t] += o;
        __syncthreads();
    }
    if (i < N_NODES) {
        row_ptr[i] = boff[blockIdx.x] + lds[t] - v;
        dinv[i] = rsqrtf((float)(v + 1));  // +1 self-loop
    }
    if (i == 0) row_ptr[N_NODES] = N_EDGES;
}

__global__ void k_fillr(const int* __restrict__ src, const int* __restrict__ dst,
                        const ushort* __restrict__ rank, const int* __restrict__ row_ptr,
                        ushort* __restrict__ csr_src) {
    int e = blockIdx.x * 256 + threadIdx.x;
    if (e >= N_EDGES) return;
    int pos = row_ptr[dst[e]] + (int)rank[e];
    csr_src[pos] = (ushort)src[e];
}

// ---------- chunked gather: one (node, 16-feat chunk) per wave-chunk pair ----------
// Table is chunk-major [8][N][8 uints]. chunk = blockIdx&7 -> XCD-sliced L2 residency.
// Wave: 8 oct-groups x 8 lanes; group g handles edges beg+g, +8, ... (2-deep unroll
// = 16 edges in flight); lane fl covers feature-uint fl (2 feats).
template<bool NVEC>
__global__ void k_gatherc(const uint* __restrict__ xh, const ushort* __restrict__ csr,
                          const int* __restrict__ rp, const float* __restrict__ dinv,
                          uint* __restrict__ outp, float* __restrict__ nvec) {
    int b = blockIdx.x;
    int c = b & 7;
    int node = (b >> 3) * 4 + (threadIdx.x >> 6);
    int lane = threadIdx.x & 63;
    int g = lane >> 3, fl = lane & 7;
    int beg = rp[node], end = rp[node + 1];
    const uint* tb = xh + (size_t)c * N_NODES * 8;
    float a0 = 0.f, a1 = 0.f, sc = 0.f;

    for (int j = beg + g; j < end; j += 16) {
        int s0 = csr[j];
        float c0 = dinv[s0];
        uint u0 = tb[(size_t)s0 * 8 + fl];
        int j1 = j + 8;
        int s1 = (j1 < end) ? (int)csr[j1] : s0;
        float c1 = (j1 < end) ? dinv[s1] : 0.f;
        uint u1 = tb[(size_t)s1 * 8 + fl];
        sc += c0 + c1;
        a0 = fmaf(c0, bf_lo(u0), a0); a1 = fmaf(c0, bf_hi(u0), a1);
        a0 = fmaf(c1, bf_lo(u1), a0); a1 = fmaf(c1, bf_hi(u1), a1);
    }
    #pragma unroll
    for (int off = 8; off < 64; off <<= 1) {
        a0 += __shfl_xor(a0, off);
        a1 += __shfl_xor(a1, off);
        if (NVEC) sc += __shfl_xor(sc, off);
    }
    if (g == 0) {
        float dd = dinv[node];
        float dd2 = dd * dd;
        uint u = tb[(size_t)node * 8 + fl];
        float o0 = fmaf(dd, a0, dd2 * bf_lo(u));
        float o1 = fmaf(dd, a1, dd2 * bf_hi(u));
        uint p = (uint)f2bf(o0) | ((uint)f2bf(o1) << 16);
        __builtin_nontemporal_store(p, &outp[((size_t)c * N_NODES + node) * 8 + fl]);
        if (NVEC && c == 0 && fl == 0) nvec[node] = fmaf(dd, sc, dd2);
    }
}

// ---------- final MFMA GEMM: out[16r][128] fp32 = G2[chunk-major] @ W12t[128][128]
//            + nvec[r]*bvec[c] + b2[c] ----------
__global__ void __launch_bounds__(256)
k_gemm_out(const ushort* __restrict__ A, const ushort* __restrict__ Wt,
           const float* __restrict__ nvec, const float* __restrict__ bvec,
           const float* __restrict__ b2, float* __restrict__ out) {
    constexpr int K = 128, NC = 128, KC = 4, TPW = 2;
    const int lane = threadIdx.x & 63;
    const int wave = threadIdx.x >> 6;
    const int row0 = blockIdx.x * 16;
    const int r = row0 + (lane & 15);
    const int ksub = (lane >> 4) * 8;

    f32x4 acc[TPW];
    int col[TPW];
    #pragma unroll
    for (int t = 0; t < TPW; ++t) {
        acc[t] = (f32x4){0.f, 0.f, 0.f, 0.f};
        col[t] = (wave * TPW + t) * 16 + (lane & 15);
    }
    #pragma unroll
    for (int kc = 0; kc < KC; ++kc) {
        // A chunk-major: feats [kc*32+ksub, +8) live in chunk c8 = kc*2 + (ksub>>4),
        // offset (ksub&15) within the 16-feat chunk row.
        int c8 = kc * 2 + (ksub >> 4);
        bf16x8 af = *(const bf16x8*)(A + ((size_t)c8 * N_NODES + r) * 16 + (ksub & 15));
        #pragma unroll
        for (int t = 0; t < TPW; ++t) {
            bf16x8 bf = *(const bf16x8*)(Wt + (size_t)col[t] * K + kc * 32 + ksub);
            acc[t] = __builtin_amdgcn_mfma_f32_16x16x32_bf16(af, bf, acc[t], 0, 0, 0);
        }
    }
    const int rb = row0 + (lane >> 4) * 4;
    float nv[4];
    #pragma unroll
    for (int e = 0; e < 4; ++e) nv[e] = nvec[rb + e];
    #pragma unroll
    for (int t = 0; t < TPW; ++t) {
        float bv = bvec[col[t]];
        float bb = b2[col[t]];
        #pragma unroll
        for (int e = 0; e < 4; ++e) {
            out[(size_t)(rb + e) * NC + col[t]] = acc[t][e] + nv[e] * bv + bb;
        }
    }
}

extern "C" void kernel_launch(void* const* d_in, const int* in_sizes, int n_in,
                              void* d_out, int out_size, void* d_ws, size_t ws_size,
                              hipStream_t stream) {
    const float* emb = (const float*)d_in[0];   // [50000][128]
    const float* W1  = (const float*)d_in[1];   // [128][256]
    const float* b1  = (const float*)d_in[2];   // [256]
    const float* W2  = (const float*)d_in[3];   // [256][128]
    const float* b2  = (const float*)d_in[4];   // [128]
    const int*   ei  = (const int*)d_in[5];     // [2][800000]
    const int* src = ei;
    const int* dst = ei + N_EDGES;

    char* ws = (char*)d_ws;
    float*  dinv    = (float*) (ws);                    // 200 KB
    int*    counts  = (int*)   (ws + (256ull << 10));   // 200 KB
    int*    row_ptr = (int*)   (ws + (512ull << 10));   // 200 KB + 4
    int*    bsum    = (int*)   (ws + (768ull << 10));   // 784 B
    int*    boff    = (int*)   (ws + (772ull << 10));   // 784 B
    ushort* rank    = (ushort*)(ws + (1ull << 20));     // 1.6 MB  (1..2.6)
    ushort* csr_src = (ushort*)(ws + (3ull << 20));     // 1.6 MB  (3..4.6)
    ushort* W12t    = (ushort*)(ws + (5ull << 20));     // 32 KB
    float*  bvec    = (float*) (ws + (5ull << 20) + (64ull << 10));   // 512 B
    float*  nvec    = (float*) (ws + (5ull << 20) + (128ull << 10));  // 200 KB
    uint*   emb_h   = (uint*)  (ws + (6ull  << 20));    // 12.8 MB (6..18.8)  chunk-major
    uint*   G       = (uint*)  (ws + (19ull << 20));    // 12.8 MB (19..31.8) chunk-major
    uint*   G2      = (uint*)  (ws + (32ull << 20));    // 12.8 MB (32..44.8) chunk-major
    float*  out     = (float*)d_out;

    // independent precomputes
    k_tobf16c<<<N_NODES * 16 / 256, 256, 0, stream>>>(emb, emb_h);
    k_w12<<<129, 128, 0, stream>>>(W1, W2, b1, W12t, bvec);

    // CSR build + normalization
    k_zero<<<NB, 256, 0, stream>>>(counts);
    k_histrank<<<(N_EDGES + 255) / 256, 256, 0, stream>>>(dst, counts, rank);
    k_blocksum<<<NB, 256, 0, stream>>>(counts, bsum);
    k_scanb<<<1, 256, 0, stream>>>(bsum, boff);
    k_scatter_rp<<<NB, 256, 0, stream>>>(counts, boff, row_ptr, dinv);
    k_fillr<<<(N_EDGES + 255) / 256, 256, 0, stream>>>(src, dst, rank, row_ptr, csr_src);

    // out = (N^2 emb) @ (W1W2) + (N·1)(b1W2) + b2   — gathers XCD-chunk-sliced
    k_gatherc<false><<<(N_NODES / 4) * 8, 256, 0, stream>>>(emb_h, csr_src, row_ptr, dinv, G, nullptr);
    k_gatherc<true><<<(N_NODES / 4) * 8, 256, 0, stream>>>(G, csr_src, row_ptr, dinv, G2, nvec);
    k_gemm_out<<<N_NODES / 16, 256, 0, stream>>>((const ushort*)G2, W12t, nvec, bvec, b2, out);
}

// Round 11
// 159.626 us; speedup vs baseline: 1.8507x; 1.8507x over previous
//
#include <hip/hip_runtime.h>

#define N_NODES 50000
#define N_EDGES 800000
#define NB 196  // ceil(N_NODES / 256)

typedef unsigned int uint;
typedef short bf16x8 __attribute__((ext_vector_type(8)));
typedef float f32x4 __attribute__((ext_vector_type(4)));

__device__ __forceinline__ ushort f2bf(float f) {
    union { float f; uint u; } v; v.f = f;
    uint r = (v.u + 0x7FFFu + ((v.u >> 16) & 1u)) >> 16;  // RNE
    return (ushort)r;
}
__device__ __forceinline__ float bf_lo(uint u) { return __uint_as_float(u << 16); }
__device__ __forceinline__ float bf_hi(uint u) { return __uint_as_float(u & 0xFFFF0000u); }

// ---------- fp32 -> bf16 row-major copy (8 floats/thread) ----------
__global__ void k_tobf16(const float* __restrict__ in, uint* __restrict__ out) {
    int t = blockIdx.x * 256 + threadIdx.x;
    const float4* i4 = (const float4*)in + (size_t)t * 2;
    float4 v0 = i4[0], v1 = i4[1];
    uint4 o;
    o.x = (uint)f2bf(v0.x) | ((uint)f2bf(v0.y) << 16);
    o.y = (uint)f2bf(v0.z) | ((uint)f2bf(v0.w) << 16);
    o.z = (uint)f2bf(v1.x) | ((uint)f2bf(v1.y) << 16);
    o.w = (uint)f2bf(v1.z) | ((uint)f2bf(v1.w) << 16);
    ((uint4*)out)[t] = o;
}

// ---------- W12 = W1@W2 (bf16, transposed) and bvec = b1@W2 (fp32) ----------
__global__ void k_w12(const float* __restrict__ W1, const float* __restrict__ W2,
                      const float* __restrict__ b1, ushort* __restrict__ W12t,
                      float* __restrict__ bvec) {
    int n = threadIdx.x;
    int k = blockIdx.x;
    float s = 0.f;
    if (k < 128) {
        for (int m = 0; m < 256; ++m) s = fmaf(W1[(size_t)k * 256 + m], W2[(size_t)m * 128 + n], s);
        W12t[(size_t)n * 128 + k] = f2bf(s);
    } else {
        for (int m = 0; m < 256; ++m) s = fmaf(b1[m], W2[(size_t)m * 128 + n], s);
        bvec[n] = s;
    }
}

// ---------- degree / CSR build ----------

__global__ void k_zero(int* counts) {
    int i = blockIdx.x * 256 + threadIdx.x;
    if (i < N_NODES) counts[i] = 0;
}

// hist + per-edge rank (atomic return value). rank < ~64 << 65536.
__global__ void k_histrank(const int* __restrict__ dst, int* __restrict__ counts,
                           ushort* __restrict__ rank) {
    int e = blockIdx.x * 256 + threadIdx.x;
    if (e < N_EDGES) rank[e] = (ushort)atomicAdd(&counts[dst[e]], 1);
}

__global__ void k_blocksum(const int* __restrict__ counts, int* __restrict__ bsum) {
    __shared__ int lds[256];
    int t = threadIdx.x;
    int i = blockIdx.x * 256 + t;
    int v = (i < N_NODES) ? counts[i] : 0;
    lds[t] = v;
    __syncthreads();
    for (int off = 128; off > 0; off >>= 1) {
        if (t < off) lds[t] += lds[t + off];
        __syncthreads();
    }
    if (t == 0) bsum[blockIdx.x] = lds[0];
}

__global__ void k_scanb(const int* __restrict__ bsum, int* __restrict__ boff) {
    __shared__ int lds[256];
    int t = threadIdx.x;
    int v = (t < NB) ? bsum[t] : 0;
    lds[t] = v;
    __syncthreads();
    for (int off = 1; off < 256; off <<= 1) {
        int o = (t >= off) ? lds[t - off] : 0;
        __syncthreads();
        lds[t] += o;
        __syncthreads();
    }
    if (t < NB) boff[t] = lds[t] - v;  // exclusive
}

__global__ void k_scatter_rp(const int* __restrict__ counts, const int* __restrict__ boff,
                             int* __restrict__ row_ptr, float* __restrict__ dinv) {
    __shared__ int lds[256];
    int t = threadIdx.x;
    int i = blockIdx.x * 256 + t;
    int v = (i < N_NODES) ? counts[i] : 0;
    lds[t] = v;
    __syncthreads();
    for (int off = 1; off < 256; off <<= 1) {
        int o = (t >= off) ? lds[t - off] : 0;
        __syncthreads();
        lds[t] += o;
        __syncthreads();
    }
    if (i < N_NODES) {
        row_ptr[i] = boff[blockIdx.x] + lds[t] - v;
        dinv[i] = rsqrtf((float)(v + 1));  // +1 self-loop
    }
    if (i == 0) row_ptr[N_NODES] = N_EDGES;
}

// atomic-free CSR fill; entry packs (src<<16) | bf16(dinv[src]).
__global__ void k_fillr(const int* __restrict__ src, const int* __restrict__ dst,
                        const ushort* __restrict__ rank, const int* __restrict__ row_ptr,
                        const float* __restrict__ dinv, uint* __restrict__ csr) {
    int e = blockIdx.x * 256 + threadIdx.x;
    if (e >= N_EDGES) return;
    int s = src[e];
    int pos = row_ptr[dst[e]] + (int)rank[e];
    csr[pos] = ((uint)s << 16) | (uint)f2bf(dinv[s]);
}

// ---------- gather aggregation over bf16 table (F=128, one wave per dst) ----------
// out_bf16[d] = bf16( dinv[d]*sum_{s} dinv[s]*x[s] + dinv[d]^2*x[d] )
// CSR entry = (src<<16)|bf16(dinv[src]) -> no per-edge dinv load.
// 4 quarter-waves x 4-deep unroll = 16 rows in flight per wave.
// NVEC: also write nvec[d] = dinv[d]*sum_s dinv[s] + dinv[d]^2.
template<bool NVEC>
__global__ void k_gather128h(const uint* __restrict__ xh, const uint* __restrict__ csr,
                             const int* __restrict__ rp, const float* __restrict__ dinv,
                             uint* __restrict__ outp, float* __restrict__ nvec) {
    int node = blockIdx.x * 4 + (threadIdx.x >> 6);
    int lane = threadIdx.x & 63;
    int q = lane >> 4;
    int fl = lane & 15;
    int beg = rp[node], end = rp[node + 1];
    const uint4* xb = (const uint4*)xh;  // row s = 16 uint4s
    float a[8];
    #pragma unroll
    for (int i = 0; i < 8; ++i) a[i] = 0.f;
    float sc = 0.f;

    for (int j = beg + q; j < end; j += 16) {
        int j1 = j + 4, j2 = j + 8, j3 = j + 12;
        uint e0 = csr[j];
        uint e1 = (j1 < end) ? csr[j1] : (e0 & 0xFFFF0000u);
        uint e2 = (j2 < end) ? csr[j2] : (e0 & 0xFFFF0000u);
        uint e3 = (j3 < end) ? csr[j3] : (e0 & 0xFFFF0000u);
        int s0 = e0 >> 16, s1 = e1 >> 16, s2 = e2 >> 16, s3 = e3 >> 16;
        float c0 = bf_lo(e0), c1 = bf_lo(e1), c2 = bf_lo(e2), c3 = bf_lo(e3);
        uint4 u0 = xb[(size_t)s0 * 16 + fl];
        uint4 u1 = xb[(size_t)s1 * 16 + fl];
        uint4 u2 = xb[(size_t)s2 * 16 + fl];
        uint4 u3 = xb[(size_t)s3 * 16 + fl];
        sc += c0 + c1 + c2 + c3;
        a[0] = fmaf(c0, bf_lo(u0.x), a[0]); a[1] = fmaf(c0, bf_hi(u0.x), a[1]);
        a[2] = fmaf(c0, bf_lo(u0.y), a[2]); a[3] = fmaf(c0, bf_hi(u0.y), a[3]);
        a[4] = fmaf(c0, bf_lo(u0.z), a[4]); a[5] = fmaf(c0, bf_hi(u0.z), a[5]);
        a[6] = fmaf(c0, bf_lo(u0.w), a[6]); a[7] = fmaf(c0, bf_hi(u0.w), a[7]);
        a[0] = fmaf(c1, bf_lo(u1.x), a[0]); a[1] = fmaf(c1, bf_hi(u1.x), a[1]);
        a[2] = fmaf(c1, bf_lo(u1.y), a[2]); a[3] = fmaf(c1, bf_hi(u1.y), a[3]);
        a[4] = fmaf(c1, bf_lo(u1.z), a[4]); a[5] = fmaf(c1, bf_hi(u1.z), a[5]);
        a[6] = fmaf(c1, bf_lo(u1.w), a[6]); a[7] = fmaf(c1, bf_hi(u1.w), a[7]);
        a[0] = fmaf(c2, bf_lo(u2.x), a[0]); a[1] = fmaf(c2, bf_hi(u2.x), a[1]);
        a[2] = fmaf(c2, bf_lo(u2.y), a[2]); a[3] = fmaf(c2, bf_hi(u2.y), a[3]);
        a[4] = fmaf(c2, bf_lo(u2.z), a[4]); a[5] = fmaf(c2, bf_hi(u2.z), a[5]);
        a[6] = fmaf(c2, bf_lo(u2.w), a[6]); a[7] = fmaf(c2, bf_hi(u2.w), a[7]);
        a[0] = fmaf(c3, bf_lo(u3.x), a[0]); a[1] = fmaf(c3, bf_hi(u3.x), a[1]);
        a[2] = fmaf(c3, bf_lo(u3.y), a[2]); a[3] = fmaf(c3, bf_hi(u3.y), a[3]);
        a[4] = fmaf(c3, bf_lo(u3.z), a[4]); a[5] = fmaf(c3, bf_hi(u3.z), a[5]);
        a[6] = fmaf(c3, bf_lo(u3.w), a[6]); a[7] = fmaf(c3, bf_hi(u3.w), a[7]);
    }
    #pragma unroll
    for (int off = 16; off < 64; off <<= 1) {
        #pragma unroll
        for (int i = 0; i < 8; ++i) a[i] += __shfl_xor(a[i], off);
        if (NVEC) sc += __shfl_xor(sc, off);
    }
    if (q == 0) {
        float dd = dinv[node];
        float dd2 = dd * dd;
        uint4 u = xb[(size_t)node * 16 + fl];
        float s[8] = { bf_lo(u.x), bf_hi(u.x), bf_lo(u.y), bf_hi(u.y),
                       bf_lo(u.z), bf_hi(u.z), bf_lo(u.w), bf_hi(u.w) };
        uint4 p;
        float o0 = fmaf(dd, a[0], dd2 * s[0]), o1 = fmaf(dd, a[1], dd2 * s[1]);
        float o2 = fmaf(dd, a[2], dd2 * s[2]), o3 = fmaf(dd, a[3], dd2 * s[3]);
        float o4 = fmaf(dd, a[4], dd2 * s[4]), o5 = fmaf(dd, a[5], dd2 * s[5]);
        float o6 = fmaf(dd, a[6], dd2 * s[6]), o7 = fmaf(dd, a[7], dd2 * s[7]);
        p.x = (uint)f2bf(o0) | ((uint)f2bf(o1) << 16);
        p.y = (uint)f2bf(o2) | ((uint)f2bf(o3) << 16);
        p.z = (uint)f2bf(o4) | ((uint)f2bf(o5) << 16);
        p.w = (uint)f2bf(o6) | ((uint)f2bf(o7) << 16);
        ((uint4*)outp)[(size_t)node * 16 + fl] = p;
        if (NVEC && fl == 0) nvec[node] = fmaf(dd, sc, dd2);
    }
}

// ---------- final MFMA GEMM: out[16r][128] fp32 = G2[16r][128]bf16 @ W12t[128][128]
//            + nvec[r]*bvec[c] + b2[c] ----------
__global__ void __launch_bounds__(256)
k_gemm_out(const ushort* __restrict__ A, const ushort* __restrict__ Wt,
           const float* __restrict__ nvec, const float* __restrict__ bvec,
           const float* __restrict__ b2, float* __restrict__ out) {
    constexpr int K = 128, NC = 128, KC = 4, TPW = 2;
    const int lane = threadIdx.x & 63;
    const int wave = threadIdx.x >> 6;
    const int row0 = blockIdx.x * 16;
    const int r = row0 + (lane & 15);
    const int ksub = (lane >> 4) * 8;

    f32x4 acc[TPW];
    int col[TPW];
    #pragma unroll
    for (int t = 0; t < TPW; ++t) {
        acc[t] = (f32x4){0.f, 0.f, 0.f, 0.f};
        col[t] = (wave * TPW + t) * 16 + (lane & 15);
    }
    #pragma unroll
    for (int kc = 0; kc < KC; ++kc) {
        bf16x8 af = *(const bf16x8*)(A + (size_t)r * K + kc * 32 + ksub);
        #pragma unroll
        for (int t = 0; t < TPW; ++t) {
            bf16x8 bf = *(const bf16x8*)(Wt + (size_t)col[t] * K + kc * 32 + ksub);
            acc[t] = __builtin_amdgcn_mfma_f32_16x16x32_bf16(af, bf, acc[t], 0, 0, 0);
        }
    }
    const int rb = row0 + (lane >> 4) * 4;
    float nv[4];
    #pragma unroll
    for (int e = 0; e < 4; ++e) nv[e] = nvec[rb + e];
    #pragma unroll
    for (int t = 0; t < TPW; ++t) {
        float bv = bvec[col[t]];
        float bb = b2[col[t]];
        #pragma unroll
        for (int e = 0; e < 4; ++e) {
            out[(size_t)(rb + e) * NC + col[t]] = acc[t][e] + nv[e] * bv + bb;
        }
    }
}

extern "C" void kernel_launch(void* const* d_in, const int* in_sizes, int n_in,
                              void* d_out, int out_size, void* d_ws, size_t ws_size,
                              hipStream_t stream) {
    const float* emb = (const float*)d_in[0];   // [50000][128]
    const float* W1  = (const float*)d_in[1];   // [128][256]
    const float* b1  = (const float*)d_in[2];   // [256]
    const float* W2  = (const float*)d_in[3];   // [256][128]
    const float* b2  = (const float*)d_in[4];   // [128]
    const int*   ei  = (const int*)d_in[5];     // [2][800000]
    const int* src = ei;
    const int* dst = ei + N_EDGES;

    char* ws = (char*)d_ws;
    float*  dinv    = (float*) (ws);                    // 200 KB
    int*    counts  = (int*)   (ws + (256ull << 10));   // 200 KB
    int*    row_ptr = (int*)   (ws + (512ull << 10));   // 200 KB + 4
    int*    bsum    = (int*)   (ws + (768ull << 10));   // 784 B
    int*    boff    = (int*)   (ws + (772ull << 10));   // 784 B
    ushort* rank    = (ushort*)(ws + (1ull << 20));     // 1.6 MB  (1..2.6)
    uint*   csr     = (uint*)  (ws + (3ull << 20));     // 3.2 MB  (3..6.2)
    ushort* W12t    = (ushort*)(ws + (6656ull << 10));  // 32 KB   (6.5MB)
    float*  bvec    = (float*) (ws + (6720ull << 10));  // 512 B
    float*  nvec    = (float*) (ws + (6784ull << 10));  // 200 KB
    uint*   emb_h   = (uint*)  (ws + (7ull  << 20));    // 12.8 MB (7..19.8)
    uint*   G       = (uint*)  (ws + (20ull << 20));    // 12.8 MB (20..32.8)
    uint*   G2      = (uint*)  (ws + (33ull << 20));    // 12.8 MB (33..45.8)
    float*  out     = (float*)d_out;

    // independent precomputes
    k_tobf16<<<N_NODES * 128 / 8 / 256, 256, 0, stream>>>(emb, emb_h);
    k_w12<<<129, 128, 0, stream>>>(W1, W2, b1, W12t, bvec);

    // CSR build + normalization
    k_zero<<<NB, 256, 0, stream>>>(counts);
    k_histrank<<<(N_EDGES + 255) / 256, 256, 0, stream>>>(dst, counts, rank);
    k_blocksum<<<NB, 256, 0, stream>>>(counts, bsum);
    k_scanb<<<1, 256, 0, stream>>>(bsum, boff);
    k_scatter_rp<<<NB, 256, 0, stream>>>(counts, boff, row_ptr, dinv);
    k_fillr<<<(N_EDGES + 255) / 256, 256, 0, stream>>>(src, dst, rank, row_ptr, dinv, csr);

    // out = (N^2 emb) @ (W1W2) + (N·1)(b1W2) + b2
    k_gather128h<false><<<12500, 256, 0, stream>>>(emb_h, csr, row_ptr, dinv, G, nullptr);
    k_gather128h<true><<<12500, 256, 0, stream>>>(G, csr, row_ptr, dinv, G2, nvec);
    k_gemm_out<<<N_NODES / 16, 256, 0, stream>>>((const ushort*)G2, W12t, nvec, bvec, b2, out);
}